// Round 9
// baseline (266.627 us; speedup 1.0000x reference)
//
#include <hip/hip_runtime.h>

// LinearCrossAttention: B=16, N=4096, M=1024, C_in=C_cond=512, HIDDEN=512
#define KDIM 512

typedef __attribute__((ext_vector_type(8))) short bf16x8;
typedef __attribute__((ext_vector_type(4))) float f32x4;
typedef unsigned short u16;
typedef unsigned int u32;

static __device__ __forceinline__ u16 f2bf(float f) {
  u32 u = __builtin_bit_cast(u32, f);
  u32 r = u + 0x7fffu + ((u >> 16) & 1u);   // round-to-nearest-even
  return (u16)(r >> 16);
}
static __device__ __forceinline__ bf16x8 ld_frag(const u16* p) {
  uint2 lo = *(const uint2*)p;
  uint2 hi = *(const uint2*)(p + 4);
  uint4 u = make_uint4(lo.x, lo.y, hi.x, hi.y);
  return __builtin_bit_cast(bf16x8, u);
}

// ---------------------------------------------------------------------------
// prep: f32 -> bf16 (for Wkv), 8 elems/thread
// ---------------------------------------------------------------------------
__global__ __launch_bounds__(256) void cvt_f32_bf16(
    const float* __restrict__ src, u16* __restrict__ dst, int n8)
{
  int i = blockIdx.x * 256 + threadIdx.x;
  if (i >= n8) return;
  float4 a = *(const float4*)(src + (long)i * 8);
  float4 b = *(const float4*)(src + (long)i * 8 + 4);
  u32 w0 = (u32)f2bf(a.x) | ((u32)f2bf(a.y) << 16);
  u32 w1 = (u32)f2bf(a.z) | ((u32)f2bf(a.w) << 16);
  u32 w2 = (u32)f2bf(b.x) | ((u32)f2bf(b.y) << 16);
  u32 w3 = (u32)f2bf(b.z) | ((u32)f2bf(b.w) << 16);
  *(uint4*)(dst + (long)i * 8) = make_uint4(w0, w1, w2, w3);
}

// ---------------------------------------------------------------------------
// gemm_q: BM=512, BN=64, BK=32.  512 thr = 8 waves, wave w owns rows
// [mtile + w*64, +64) x 64 cols (acc = 4x4 frags = 64 AGPR -> ~128 unified
// regs/wave -> 4 waves/SIMD -> 2 independent blocks/CU).
// A (bf16 [*,512], small L2-resident panel): MFMA fragments loaded DIRECTLY
// from global — one dwordx4/lane touches 16 full 64B lines.  No LDS for A
// (R8's LDS pipe was critical at ~1730cy/K-step vs 1242cy MFMA).
// B (f32 [512,ldn], the streaming operand): transposed+cvt through tiny LDS
// (2 x 4.6KB double buffer), depth-2 register prefetch, coalesced float2
// row-pair loads, kpair-quad XOR swizzle:
//   elem B[k][n] at u32 idx n*18 + ((k>>1) ^ ((n&3)<<2))  [+pad 2/row]
//   frag reads: bank-pair P=(9n+2(lkh^(n&3)))%16 hits all 16 -> conflict-free.
// XCD clustering (benign form, R3-proven): batch pinned to XCD so each L2
// holds 2 batches' A-panels; co-located blocks stream DISTINCT B-slices.
// ---------------------------------------------------------------------------
#define Q_LOADB(ra, rb, kt) { \
  ra = *(const float2*)(Bb + (long)((kt) + 2 * kp)     * ldn + n2); \
  rb = *(const float2*)(Bb + (long)((kt) + 2 * kp + 1) * ldn + n2); }

#define Q_STAGE(ra, rb, buf) { \
  u32 w0_ = (u32)f2bf(ra.x) | ((u32)f2bf(rb.x) << 16); \
  u32 w1_ = (u32)f2bf(ra.y) | ((u32)f2bf(rb.y) << 16); \
  u32* B32_ = (u32*)Bsh + (buf) * (64 * 18); \
  B32_[n2 * 18 + (kp ^ ((n2 & 3) << 2))]        = w0_; \
  B32_[(n2 + 1) * 18 + (kp ^ (((n2 + 1) & 3) << 2))] = w1_; }

#define Q_STEP(kt, buf) { \
  bf16x8 af_[4], bfr_[4]; \
  _Pragma("unroll") for (int mi_ = 0; mi_ < 4; ++mi_) \
    af_[mi_] = *(const bf16x8*)(Aw + (long)(mi_ * 16) * KDIM + (kt)); \
  _Pragma("unroll") for (int ni_ = 0; ni_ < 4; ++ni_) { \
    int n_ = ni_ * 16 + lrow; \
    bfr_[ni_] = ld_frag(&Bsh[(buf) * (64 * 36) + n_ * 36 + ((lkh ^ (n_ & 3)) * 8)]); } \
  __builtin_amdgcn_s_setprio(1); \
  _Pragma("unroll") for (int mi_ = 0; mi_ < 4; ++mi_) \
    _Pragma("unroll") for (int ni_ = 0; ni_ < 4; ++ni_) \
      acc[mi_][ni_] = __builtin_amdgcn_mfma_f32_16x16x32_bf16(af_[mi_], bfr_[ni_], acc[mi_][ni_], 0, 0, 0); \
  __builtin_amdgcn_s_setprio(0); }

template<bool OUT_BF16, bool BIAS, int MT_BITS, int NT>
__global__ __launch_bounds__(512, 4) void gemm_q(
    const u16* __restrict__ Ap, long a_bstride,
    const float* __restrict__ Bp, long b_bstride,
    void* __restrict__ Op, long o_bstride,
    const float* __restrict__ bias, int ldn)
{
  constexpr int MT = 1 << MT_BITS;
  __shared__ u16 Bsh[2 * 64 * 36];          // 9.2 KB total

  // decode: bits 0-2 = xcd -> batch-lo, bit 3 = batch-hi, then mt, nt
  const int d = blockIdx.x;
  const int b = (d & 7) | (((d >> 3) & 1) << 3);
  const int rest = d >> 4;
  const int mt = rest & (MT - 1);
  const int nt = rest >> MT_BITS;
  const long mtile = (long)mt * 512;
  const long ntile = (long)nt * 64;
  const u16* Ab = Ap + (long)b * a_bstride + mtile * KDIM;
  const float* Bb = Bp + (long)b * b_bstride + ntile;

  const int t = threadIdx.x;
  const int lane = t & 63, wv = t >> 6;
  const int lrow = lane & 15, lkh = lane >> 4;

  // B staging map: thread loads rows (kt+2kp, +1), cols (n2, n2+1) as 2 float2
  const int n2 = (t & 31) * 2;
  const int kp = t >> 5;                    // 0..15

  // per-lane A fragment base (direct-from-global path)
  const u16* Aw = Ab + (long)(wv * 64 + lrow) * KDIM + lkh * 8;

  f32x4 acc[4][4] = {};
  float2 p0a, p0b, p1a, p1b;

  // ---- prologue: fill both prefetch sets, stage step 0 ----
  Q_LOADB(p0a, p0b, 0)
  Q_LOADB(p1a, p1b, 32)
  Q_STAGE(p0a, p0b, 0)
  __syncthreads();

  for (int s2 = 0; s2 < 8; ++s2) {          // 16 K-steps as even/odd pairs
    const int kt = s2 * 64;
    // even: compute buf0; prefetch set0 <- k+64; stage set1 -> buf1
    if (s2 < 7) Q_LOADB(p0a, p0b, kt + 64)
    Q_STEP(kt, 0)
    Q_STAGE(p1a, p1b, 1)
    __syncthreads();
    // odd: compute buf1; prefetch set1 <- k+96; stage set0 -> buf0
    if (s2 < 7) Q_LOADB(p1a, p1b, kt + 96)
    Q_STEP(kt + 32, 1)
    if (s2 < 7) {
      Q_STAGE(p0a, p0b, 0)
      __syncthreads();
    }
  }

  // ---- epilogue: scalar stores, 16 lanes x 4B = 64B contiguous per instr ----
  #pragma unroll
  for (int mi = 0; mi < 4; ++mi) {
    #pragma unroll
    for (int r = 0; r < 4; ++r) {
      long gr = mtile + wv * 64 + mi * 16 + lkh * 4 + r;
      float bv = 0.0f;
      if constexpr (BIAS) bv = bias[gr];
      #pragma unroll
      for (int ni = 0; ni < 4; ++ni) {
        long gc = ntile + ni * 16 + lrow;
        float v = acc[mi][ni][r] + bv;
        if constexpr (OUT_BF16)
          ((u16*)Op)[(long)b * o_bstride + gr * ldn + gc] = f2bf(v);
        else
          ((float*)Op)[(long)b * o_bstride + gr * ldn + gc] = v;
      }
    }
  }
}

// ---------------------------------------------------------------------------
// K2: per (b,h): softmax over m of K rows, ctx[d][e] = sum_m Kexp[d][m]*V[e][m]
// ---------------------------------------------------------------------------
__global__ __launch_bounds__(256, 2) void softmax_context(
    const u16* __restrict__ kv, float* __restrict__ ctx)
{
  constexpr int LDE = 132;
  __shared__ float rowmax[64], rowinv[64];
  __shared__ u16 Ke[64 * LDE];
  __shared__ u16 Vs[64 * LDE];
  __shared__ float pr[64 * 68];

  const int bh = blockIdx.x;
  const u16* Kr = kv + (long)(bh >> 3) * (1024 * 1024) + (long)(bh & 7) * (64 * 1024);
  const u16* Vr = Kr + 512 * 1024;

  const int t = threadIdx.x;
  const int lane = t & 63, wv = t >> 6;
  const int lrow = lane & 15, lkh = lane >> 4;
  const int d4 = t >> 2, q4 = t & 3;

  {
    const u16* row = Kr + d4 * 1024 + q4 * 256;
    float mx = -3e38f;
    for (int i = 0; i < 256; i += 8) {
      uint4 v = *(const uint4*)(row + i);
      u32 ws[4] = {v.x, v.y, v.z, v.w};
      #pragma unroll
      for (int j = 0; j < 4; ++j) {
        mx = fmaxf(mx, __builtin_bit_cast(float, ws[j] << 16));
        mx = fmaxf(mx, __builtin_bit_cast(float, ws[j] & 0xffff0000u));
      }
    }
    mx = fmaxf(mx, __shfl_xor(mx, 1));
    mx = fmaxf(mx, __shfl_xor(mx, 2));
    float s = 0.f;
    for (int i = 0; i < 256; i += 8) {
      uint4 v = *(const uint4*)(row + i);
      u32 ws[4] = {v.x, v.y, v.z, v.w};
      #pragma unroll
      for (int j = 0; j < 4; ++j) {
        s += __expf(__builtin_bit_cast(float, ws[j] << 16) - mx);
        s += __expf(__builtin_bit_cast(float, ws[j] & 0xffff0000u) - mx);
      }
    }
    s += __shfl_xor(s, 1);
    s += __shfl_xor(s, 2);
    if (q4 == 0) { rowmax[d4] = mx; rowinv[d4] = 1.f / s; }
  }
  __syncthreads();

  f32x4 cacc[4][4] = {};

  for (int mc = 0; mc < 8; ++mc) {
    {
      int dd = t >> 2, j = t & 3;
      int m0 = mc * 128 + j * 32;
      float mx = rowmax[dd], inv = rowinv[dd];
      const u16* src = Kr + dd * 1024 + m0;
      u16* dst = &Ke[dd * LDE + j * 32];
      #pragma unroll
      for (int cq = 0; cq < 4; ++cq) {
        uint4 v = *(const uint4*)(src + cq * 8);
        u32 in[4] = {v.x, v.y, v.z, v.w};
        u32 out[4];
        #pragma unroll
        for (int j2 = 0; j2 < 4; ++j2) {
          float lo = __builtin_bit_cast(float, in[j2] << 16);
          float hif = __builtin_bit_cast(float, in[j2] & 0xffff0000u);
          out[j2] = (u32)f2bf(__expf(lo - mx) * inv) |
                    ((u32)f2bf(__expf(hif - mx) * inv) << 16);
        }
        *(uint2*)(dst + cq * 8)     = make_uint2(out[0], out[1]);
        *(uint2*)(dst + cq * 8 + 4) = make_uint2(out[2], out[3]);
      }
      const u16* vsrc = Vr + dd * 1024 + m0;
      u16* vdst = &Vs[dd * LDE + j * 32];
      #pragma unroll
      for (int cq = 0; cq < 4; ++cq) {
        uint4 v = *(const uint4*)(vsrc + cq * 8);
        *(uint2*)(vdst + cq * 8)     = make_uint2(v.x, v.y);
        *(uint2*)(vdst + cq * 8 + 4) = make_uint2(v.z, v.w);
      }
    }
    __syncthreads();
    bf16x8 ka[4], vb[4];
    #pragma unroll
    for (int mi = 0; mi < 4; ++mi)
      ka[mi] = ld_frag(&Ke[(mi * 16 + lrow) * LDE + wv * 32 + lkh * 8]);
    #pragma unroll
    for (int ni = 0; ni < 4; ++ni)
      vb[ni] = ld_frag(&Vs[(ni * 16 + lrow) * LDE + wv * 32 + lkh * 8]);
    #pragma unroll
    for (int mi = 0; mi < 4; ++mi)
      #pragma unroll
      for (int ni = 0; ni < 4; ++ni)
        cacc[mi][ni] = __builtin_amdgcn_mfma_f32_16x16x32_bf16(ka[mi], vb[ni], cacc[mi][ni], 0, 0, 0);
    __syncthreads();
  }

  for (int w = 0; w < 4; ++w) {
    if (wv == w) {
      #pragma unroll
      for (int mi = 0; mi < 4; ++mi)
        #pragma unroll
        for (int ni = 0; ni < 4; ++ni)
          #pragma unroll
          for (int r = 0; r < 4; ++r) {
            float* p = &pr[(mi * 16 + lkh * 4 + r) * 68 + (ni * 16 + lrow)];
            float v = cacc[mi][ni][r];
            if (w == 0) *p = v; else *p += v;
          }
    }
    __syncthreads();
  }
  float* cg = ctx + (long)bh * 4096;
  for (int i = 0; i < 16; ++i) {
    int o = t + i * 256;
    cg[o] = 0.125f * pr[(o >> 6) * 68 + (o & 63)];  // fold q-scale
  }
}

// ---------------------------------------------------------------------------
// K3a: U[b][o][h*64+d] = sum_e Wo[o][h*64+e] * ctx[b,h,d,e]
// ---------------------------------------------------------------------------
__global__ __launch_bounds__(256) void compose_u(
    const float* __restrict__ ctx, const float* __restrict__ Wo, u16* __restrict__ U)
{
  __shared__ float cs[16 * 64];
  const int bh = blockIdx.x, dq = blockIdx.y;
  const int b = bh >> 3, h = bh & 7;
  const int t = threadIdx.x;
  const float* cgrp = ctx + (long)bh * 4096 + dq * 16 * 64;
  for (int i = t; i < 1024; i += 256) cs[i] = cgrp[i];
  __syncthreads();
  #pragma unroll
  for (int rep = 0; rep < 2; ++rep) {
    int o = rep * 256 + t;
    const float* wrow = Wo + (long)o * 512 + h * 64;
    float acc[16] = {};
    for (int e = 0; e < 64; ++e) {
      float w = wrow[e];
      #pragma unroll
      for (int dd = 0; dd < 16; ++dd) acc[dd] += w * cs[dd * 64 + e];
    }
    u16* urow = U + (long)b * (512 * 512) + (long)o * 512 + h * 64 + dq * 16;
    #pragma unroll
    for (int dd = 0; dd < 16; ++dd) urow[dd] = f2bf(acc[dd]);
  }
}

// ---------------------------------------------------------------------------
extern "C" void kernel_launch(void* const* d_in, const int* in_sizes, int n_in,
                              void* d_out, int out_size, void* d_ws, size_t ws_size,
                              hipStream_t stream)
{
  const float* x   = (const float*)d_in[0];  // [16, 512, 4096]
  const float* c   = (const float*)d_in[1];  // [16, 512, 1024]
  const float* Wq  = (const float*)d_in[2];  // [512, 512]
  const float* Wkv = (const float*)d_in[3];  // [1024, 512]
  const float* Wo  = (const float*)d_in[4];  // [512, 512]
  const float* bo  = (const float*)d_in[5];  // [512]

  // workspace layout (52.4 MB total)
  char* ws = (char*)d_ws;
  u16*   kv   = (u16*)ws;                      // 16*1024*1024 bf16 = 33.5 MB
  float* ctx  = (float*)(ws + 33554432);       // 16*8*64*64 f32    =  2.1 MB
  u16*   U    = (u16*)(ws + 35651584);         // 16*512*512 bf16   =  8.4 MB
  u16*   Weff = (u16*)(ws + 44040192);         // 16*512*512 bf16   =  8.4 MB
  u16*   Wkvb = (u16*)(ws + 44040192);         // 1 MB, overlaps Weff: consumed by K1
                                               // BEFORE K3b writes Weff

  // K0: Wkv f32 -> bf16
  cvt_f32_bf16<<<dim3(256), 256, 0, stream>>>(Wkv, Wkvb, 65536);
  // K1: kv[b] = Wkv @ c[b]        MT=2, NT=16 -> 512 blocks (2/CU)
  gemm_q<true, false, 1, 16><<<dim3(512), 512, 0, stream>>>(
      Wkvb, 0, c, 512L * 1024, kv, 1024L * 1024, nullptr, 1024);
  // K2: softmax + context
  softmax_context<<<dim3(128), 256, 0, stream>>>(kv, ctx);
  // K3a: U = scale * Wo_h @ ctx_h^T
  compose_u<<<dim3(128, 4), 256, 0, stream>>>(ctx, Wo, U);
  // K3b: Weff[b] = U[b] @ Wq      MT=1, NT=8  -> 128 blocks
  gemm_q<true, false, 0, 8><<<dim3(128), 512, 0, stream>>>(
      U, 512L * 512, Wq, 0, Weff, 512L * 512, nullptr, 512);
  // K4: Y[b] = Weff[b] @ x[b] + bo   MT=1, NT=64 -> 1024 blocks (4/CU queued)
  gemm_q<false, true, 0, 64><<<dim3(1024), 512, 0, stream>>>(
      Weff, 512L * 512, x, 512L * 4096, d_out, 512L * 4096, bo, 4096);
}